// Round 4
// baseline (164.727 us; speedup 1.0000x reference)
//
#include <hip/hip_runtime.h>

// Problem constants (fixed by setup_inputs)
#define NB  8     // batch
#define SS  500   // seq
#define UU  128   // units (also GH*GD)
#define NG  5     // ngrams per chunk
#define CC  100   // chunks = S/NG
#define FF  20    // 2*C(5,2) edge-concat feature width
#define HH  5     // per-chunk heads
#define HD  10    // HH * DK (DK=2)

// ht[f] = xv[EI[f]]  (interleaved pair table, compile-time indexed)
__device__ __constant__ const int EI[FF] =
    {0,1, 0,2, 0,3, 0,4, 1,2, 1,3, 1,4, 2,3, 2,4, 3,4};

template <int CTRL>
__device__ __forceinline__ float qperm(float x) {
    return __int_as_float(__builtin_amdgcn_update_dpp(
        0, __float_as_int(x), CTRL, 0xF, 0xF, true));
}
// sum over the 4 lanes of a quad (all lanes get the result) — VALU only
__device__ __forceinline__ float quad_sum(float x) {
    x += qperm<0xB1>(x);   // quad_perm [1,0,3,2]
    x += qperm<0x4E>(x);   // quad_perm [2,3,0,1]
    return x;
}
__device__ __forceinline__ unsigned bf16pk(float a, float b) {  // RNE pack
    unsigned ua = __float_as_uint(a), ub = __float_as_uint(b);
    ua = (ua + 0x7FFFu + ((ua >> 16) & 1u)) >> 16;
    ub = (ub + 0x7FFFu + ((ub >> 16) & 1u)) & 0xFFFF0000u;
    return ua | ub;
}

// ---------------------------------------------------------------------------
// K1: per-chunk edge MHA + leaky+mean+pos -> g (d_out), + graph qkv -> ws
// block = (b,c), 512 threads.  P0/P1: tid = u*4+vq (quad = one u).
// ---------------------------------------------------------------------------
__global__ __launch_bounds__(512, 6) void k1_chunk_mha(
    const float* __restrict__ x,   const float* __restrict__ wq,
    const float* __restrict__ bq,  const float* __restrict__ wk,
    const float* __restrict__ bk,  const float* __restrict__ wv,
    const float* __restrict__ bv,  const float* __restrict__ wo,
    const float* __restrict__ bo,  const float* __restrict__ pos,
    const float* __restrict__ gwq, const float* __restrict__ gbq,
    const float* __restrict__ gwk, const float* __restrict__ gbk,
    const float* __restrict__ gwv, const float* __restrict__ gbv,
    float* __restrict__ g_out, float* __restrict__ gq_out,
    float* __restrict__ gk_out, float* __restrict__ gv_out)
{
    const int bc  = blockIdx.x;
    const int b   = bc / CC, c = bc % CC;
    const int tid = threadIdx.x;
    const int u   = tid >> 2;          // 0..127
    const int vq  = tid & 3;           // quad lane

    __shared__ uint4 s_k4[HH * 32];    // bf16 (k0,k1) per (h, pos), 4 pos/uint4
    __shared__ uint4 s_v4[HH * 32];
    __shared__ float s_g[UU];
    __shared__ float s_gr[4][3][UU];   // graph-qkv partials
    unsigned* s_k = (unsigned*)s_k4;
    unsigned* s_v = (unsigned*)s_v4;

    // ---------------- P0: x, projection for this thread's role ----------
    float xv[NG];
    const float* xb = x + (size_t)b * SS * UU + (size_t)c * NG * UU + u;
#pragma unroll
    for (int t = 0; t < NG; ++t) xv[t] = xb[t * UU];

    // roles: vq 0,3 -> q ; vq 1 -> k ; vq 2 -> v
    const float* wsel = (vq == 1) ? wk : (vq == 2) ? wv : wq;
    const float* bsel = (vq == 1) ? bk : (vq == 2) ? bv : bq;
    float p[HD];
    {
        const float2* bs2 = (const float2*)(bsel + c * HD);
#pragma unroll
        for (int d2 = 0; d2 < 5; ++d2) {
            const float2 t2 = bs2[d2];
            p[2*d2] = t2.x; p[2*d2+1] = t2.y;
        }
        const float2* w2 = (const float2*)(wsel + c * (FF * HD));
#pragma unroll
        for (int f = 0; f < FF; ++f) {
            const float hf = xv[EI[f]];            // compile-time index
#pragma unroll
            for (int d2 = 0; d2 < 5; ++d2) {
                const float2 t2 = w2[f*5 + d2];
                p[2*d2]   = fmaf(hf, t2.x, p[2*d2]);
                p[2*d2+1] = fmaf(hf, t2.y, p[2*d2+1]);
            }
        }
    }
    if (vq == 1) {
#pragma unroll
        for (int h = 0; h < HH; ++h) s_k[h*UU + u] = bf16pk(p[2*h], p[2*h+1]);
    } else if (vq == 2) {
#pragma unroll
        for (int h = 0; h < HH; ++h) s_v[h*UU + u] = bf16pk(p[2*h], p[2*h+1]);
    }
    // q broadcast from quad lane 0 (DPP, no barrier needed within wave)
    const float scale = 0.7071067811865476f;       // 1/sqrt(dk=2)
    float q0[HH], q1[HH];
#pragma unroll
    for (int h = 0; h < HH; ++h) {
        q0[h] = qperm<0x00>(p[2*h])   * scale;     // quad_perm [0,0,0,0]
        q1[h] = qperm<0x00>(p[2*h+1]) * scale;
    }
    __syncthreads();                               // B1: s_k/s_v ready

    // ---------------- P1: attention partials over vq's 32 positions -----
    float l[HH], o0[HH], o1[HH];
#pragma unroll
    for (int h = 0; h < HH; ++h) { l[h] = 0.f; o0[h] = 0.f; o1[h] = 0.f; }
#pragma unroll
    for (int h = 0; h < HH; ++h) {
#pragma unroll
        for (int j = 0; j < 8; ++j) {
            // vq-rotated so the 4 multicast addresses hit disjoint bank quads
            const int i4 = h*32 + vq*8 + ((j + 2*vq) & 7);
            const uint4 kk = s_k4[i4];
            const uint4 vv = s_v4[i4];
            const unsigned kw[4] = {kk.x, kk.y, kk.z, kk.w};
            const unsigned vw[4] = {vv.x, vv.y, vv.z, vv.w};
#pragma unroll
            for (int m = 0; m < 4; ++m) {
                const float k0 = __uint_as_float(kw[m] << 16);
                const float k1 = __uint_as_float(kw[m] & 0xFFFF0000u);
                const float s  = fmaf(q0[h], k0, q1[h] * k1);
                const float e  = __expf(s);        // |s|<~1: shift-free exact
                l[h] += e;
                o0[h] = fmaf(e, __uint_as_float(vw[m] << 16),         o0[h]);
                o1[h] = fmaf(e, __uint_as_float(vw[m] & 0xFFFF0000u), o1[h]);
            }
        }
    }
    // quad reduce (VALU DPP) -> every lane gets full o for its u
    float o[HD];
#pragma unroll
    for (int h = 0; h < HH; ++h) {
        const float L  = quad_sum(l[h]);
        const float O0 = quad_sum(o0[h]);
        const float O1 = quad_sum(o1[h]);
        const float inv = 1.f / L;
        o[2*h] = O0 * inv; o[2*h+1] = O1 * inv;
    }

    // out-proj + residual + leaky(0.3) + mean: all lanes, all 20 f's
    // (wo/bo indices block-uniform -> scalar loads; 4x redundant but barrier-free)
    const float* woc = wo + c * (HD * FF);
    const float* boc = bo + c * FF;
    float gsum = 0.f;
#pragma unroll
    for (int f = 0; f < FF; ++f) {
        float acc = boc[f];
#pragma unroll
        for (int hd = 0; hd < HD; ++hd) acc = fmaf(o[hd], woc[hd*FF + f], acc);
        const float a = xv[EI[f]] + acc;
        gsum += (a > 0.f) ? a : 0.3f * a;
    }
    const float g = gsum * (1.f / FF) + pos[c*UU + u];
    if (vq == 0) {
        g_out[(size_t)bc*UU + u] = g;
        s_g[u] = g;
    }
    __syncthreads();                               // B2: s_g ready

    // ---------------- P2: graph qkv partials; remap: (ug, quarter) ------
    const int ug = tid & 127, pp = tid >> 7;
    float aq = 0.f, ak = 0.f, av = 0.f;
#pragma unroll 4
    for (int i = 0; i < 32; ++i) {
        const int u2 = pp*32 + i;
        const float gu = s_g[u2];                  // uniform -> broadcast
        aq = fmaf(gu, gwq[u2*UU + ug], aq);        // coalesced across ug
        ak = fmaf(gu, gwk[u2*UU + ug], ak);
        av = fmaf(gu, gwv[u2*UU + ug], av);
    }
    s_gr[pp][0][ug] = aq; s_gr[pp][1][ug] = ak; s_gr[pp][2][ug] = av;
    __syncthreads();                               // B3

    // ---------------- P3: final sums + stores ---------------------------
    if (pp < 3) {
        const float s = s_gr[0][pp][ug] + s_gr[1][pp][ug]
                      + s_gr[2][pp][ug] + s_gr[3][pp][ug];
        if (pp == 0)
            gq_out[(size_t)bc*UU + ug] = (s + gbq[ug]) * 0.17677669529663687f;
        else if (pp == 1)
            gk_out[(size_t)bc*UU + ug] = s + gbk[ug];
        else
            gv_out[(size_t)bc*UU + ug] = s + gbv[ug];
    }
}

// ---------------------------------------------------------------------------
// K2: graph attention + out-proj + residual. block=(b,q), 256 threads.
// ---------------------------------------------------------------------------
#define GHH 4
__global__ __launch_bounds__(256) void k2_graph(
    const float* __restrict__ gq, const float* __restrict__ gk,
    const float* __restrict__ gv, const float* __restrict__ gwo,
    const float* __restrict__ gbo, float* __restrict__ out)
{
    const int bq = blockIdx.x;
    const int b  = bq / CC;
    const int t  = threadIdx.x;

    __shared__ float s_q[UU];
    __shared__ float s_e[GHH][CC];
    __shared__ float s_pa[2][UU];   // o partials
    __shared__ float s_pl[2][UU];   // l partials
    __shared__ float s_o[UU];
    __shared__ float s_p3[2][UU];

    float gval = 0.f;
    if (t < UU) {
        gval  = out[(size_t)bq*UU + t];            // g (written by K1)
        s_q[t] = gq[(size_t)bq*UU + t];            // already scaled
    }
    __syncthreads();

    // phase 1: scores+exp; thread = (k, head-pair)
    if (t < 200) {
        const int k  = (t < 100) ? t : t - 100;
        const int h0 = (t < 100) ? 0 : 2;
        const float4* krow = (const float4*)(gk + ((size_t)b*CC + k)*UU);
        const float4* q4   = (const float4*)s_q;   // uniform -> broadcast
#pragma unroll
        for (int hh = 0; hh < 2; ++hh) {
            const int h = h0 + hh;
            float s = 0.f;
#pragma unroll
            for (int i = 0; i < 8; ++i) {
                const float4 kf = krow[h*8 + i];
                const float4 qf = q4[h*8 + i];
                s = fmaf(qf.x, kf.x, s); s = fmaf(qf.y, kf.y, s);
                s = fmaf(qf.z, kf.z, s); s = fmaf(qf.w, kf.w, s);
            }
            s_e[h][k] = __expf(s);                 // scores tiny: shift-free
        }
    }
    __syncthreads();

    // phase 2: o/l partials; thread = (d, k-half)
    {
        const int d = t & 127, kh = t >> 7, h = d >> 5;
        const float* vcol = gv + (size_t)b*CC*UU + d;
        float l = 0.f, o = 0.f;
#pragma unroll 5
        for (int i = 0; i < 50; ++i) {
            const int k = kh*50 + i;
            const float e = s_e[h][k];
            l += e;
            o = fmaf(e, vcol[(size_t)k*UU], o);    // coalesced across d
        }
        s_pa[kh][d] = o; s_pl[kh][d] = l;
    }
    __syncthreads();
    if (t < UU) s_o[t] = (s_pa[0][t] + s_pa[1][t]) / (s_pl[0][t] + s_pl[1][t]);
    __syncthreads();

    // phase 3: out-proj partials; thread = (u, hd-half)
    {
        const int u = t & 127, half = t >> 7;
        float acc = 0.f;
#pragma unroll 4
        for (int i = 0; i < 64; ++i) {
            const int hd = half*64 + i;
            acc = fmaf(s_o[hd], gwo[hd*UU + u], acc);  // coalesced across u
        }
        s_p3[half][u] = acc;
    }
    __syncthreads();
    if (t < UU)
        out[(size_t)bq*UU + t] = gval + s_p3[0][t] + s_p3[1][t] + gbo[t];
}

extern "C" void kernel_launch(void* const* d_in, const int* in_sizes, int n_in,
                              void* d_out, int out_size, void* d_ws, size_t ws_size,
                              hipStream_t stream)
{
    (void)in_sizes; (void)n_in; (void)out_size; (void)ws_size;
    const float* x   = (const float*)d_in[0];
    const float* wq  = (const float*)d_in[1];
    const float* bq  = (const float*)d_in[2];
    const float* wk  = (const float*)d_in[3];
    const float* bk  = (const float*)d_in[4];
    const float* wv  = (const float*)d_in[5];
    const float* bv  = (const float*)d_in[6];
    const float* wo  = (const float*)d_in[7];
    const float* bo  = (const float*)d_in[8];
    const float* pos = (const float*)d_in[9];
    const float* gwq = (const float*)d_in[10];
    const float* gbq = (const float*)d_in[11];
    const float* gwk = (const float*)d_in[12];
    const float* gbk = (const float*)d_in[13];
    const float* gwv = (const float*)d_in[14];
    const float* gbv = (const float*)d_in[15];
    const float* gwo = (const float*)d_in[16];
    const float* gbo = (const float*)d_in[17];
    float* out = (float*)d_out;
    float* ws  = (float*)d_ws;

    float* gq_ws = ws;              // [8*100*128]
    float* gk_ws = ws + 102400;
    float* gv_ws = ws + 204800;

    k1_chunk_mha<<<NB*CC, 512, 0, stream>>>(x, wq, bq, wk, bk, wv, bv, wo, bo,
        pos, gwq, gbq, gwk, gbk, gwv, gbv, out, gq_ws, gk_ws, gv_ws);
    k2_graph<<<NB*CC, 256, 0, stream>>>(gq_ws, gk_ws, gv_ws, gwo, gbo, out);
}

// Round 5
// 129.723 us; speedup vs baseline: 1.2698x; 1.2698x over previous
//
#include <hip/hip_runtime.h>

// Problem constants (fixed by setup_inputs)
#define NB  8     // batch
#define SS  500   // seq
#define UU  128   // units (also GH*GD)
#define NG  5     // ngrams per chunk
#define CC  100   // chunks = S/NG
#define FF  20    // 2*C(5,2) edge-concat feature width
#define HH  5     // per-chunk heads
#define HD  10    // HH * DK (DK=2)

// ht[f] = xv[EI[f]]  (interleaved pair table, compile-time indexed)
__device__ __constant__ const int EI[FF] =
    {0,1, 0,2, 0,3, 0,4, 1,2, 1,3, 1,4, 2,3, 2,4, 3,4};

// qkv projection: weights block-uniform (c) -> scalar s_load broadcasts
__device__ __forceinline__ void proj10(const float* __restrict__ w,
                                       const float* __restrict__ bias,
                                       int c, const float xv[NG], float p[HD])
{
    const float2* bs2 = (const float2*)(bias + c * HD);
#pragma unroll
    for (int d2 = 0; d2 < 5; ++d2) {
        const float2 t2 = bs2[d2];
        p[2*d2] = t2.x; p[2*d2+1] = t2.y;
    }
    const float2* w2 = (const float2*)(w + c * (FF * HD));
#pragma unroll
    for (int f = 0; f < FF; ++f) {
        const float hf = xv[EI[f]];               // compile-time index
#pragma unroll
        for (int d2 = 0; d2 < 5; ++d2) {
            const float2 t2 = w2[f*5 + d2];
            p[2*d2]   = fmaf(hf, t2.x, p[2*d2]);
            p[2*d2+1] = fmaf(hf, t2.y, p[2*d2+1]);
        }
    }
}

// ---------------------------------------------------------------------------
// K1: per-chunk edge MHA + leaky+mean+pos -> g (d_out), + graph qkv -> ws
// block = (b,c), 512 threads.  vq = tid>>7 (uniform per wave-pair), u = tid&127.
// P0: vq0 -> q, vq1 -> k, vq2 -> v projection (wave-uniform weight addrs).
// P1: thread (vq,u) does attention partials for u over v in [vq*32, vq*32+32).
// ---------------------------------------------------------------------------
__global__ __launch_bounds__(512, 6) void k1_chunk_mha(
    const float* __restrict__ x,   const float* __restrict__ wq,
    const float* __restrict__ bq,  const float* __restrict__ wk,
    const float* __restrict__ bk,  const float* __restrict__ wv,
    const float* __restrict__ bv,  const float* __restrict__ wo,
    const float* __restrict__ bo,  const float* __restrict__ pos,
    const float* __restrict__ gwq, const float* __restrict__ gbq,
    const float* __restrict__ gwk, const float* __restrict__ gbk,
    const float* __restrict__ gwv, const float* __restrict__ gbv,
    float* __restrict__ g_out, float* __restrict__ gq_out,
    float* __restrict__ gk_out, float* __restrict__ gv_out)
{
    const int bc  = blockIdx.x;
    const int b   = bc / CC, c = bc % CC;
    const int tid = threadIdx.x;
    const int u   = tid & 127;
    const int vq  = tid >> 7;            // 0..3, uniform per wave-pair

    __shared__ float  s_q[HD][UU];       // scaled q
    __shared__ float4 s_kv[HH][UU];      // (k0,k1,v0,v1) per (head, pos)
    __shared__ float  s_g[UU];
    __shared__ float  s_part[4][HH*3][UU];   // (l,o0,o1) per vq,head  (30.7 KB)
    float (*s_gr)[3][UU] = (float (*)[3][UU])s_part;  // aliased after B3

    // ---------------- P0: x load + role projection -----------------------
    float xv[NG];
    if (vq < 3) {
        const float* xb = x + (size_t)b * SS * UU + (size_t)c * NG * UU + u;
#pragma unroll
        for (int t = 0; t < NG; ++t) xv[t] = xb[t * UU];   // coalesced
    }
    if (vq == 0) {
        float p[HD];
        proj10(wq, bq, c, xv, p);
        const float scale = 0.7071067811865476f;   // 1/sqrt(dk=2)
#pragma unroll
        for (int i = 0; i < HD; ++i) s_q[i][u] = p[i] * scale;
    } else if (vq == 1) {
        float p[HD];
        proj10(wk, bk, c, xv, p);
#pragma unroll
        for (int h = 0; h < HH; ++h) { s_kv[h][u].x = p[2*h]; s_kv[h][u].y = p[2*h+1]; }
    } else if (vq == 2) {
        float p[HD];
        proj10(wv, bv, c, xv, p);
#pragma unroll
        for (int h = 0; h < HH; ++h) { s_kv[h][u].z = p[2*h]; s_kv[h][u].w = p[2*h+1]; }
    }
    __syncthreads();                               // B1: q/k/v ready

    // ---------------- P1: attention partials over vq's 32 positions ------
    float q0[HH], q1[HH];
#pragma unroll
    for (int h = 0; h < HH; ++h) { q0[h] = s_q[2*h][u]; q1[h] = s_q[2*h+1][u]; }
    float l[HH], o0[HH], o1[HH];
#pragma unroll
    for (int h = 0; h < HH; ++h) { l[h] = 0.f; o0[h] = 0.f; o1[h] = 0.f; }
    const int base = vq * 32;                      // wave-uniform
#pragma unroll
    for (int h = 0; h < HH; ++h) {
#pragma unroll 8
        for (int i = 0; i < 32; ++i) {
            const float4 kv = s_kv[h][base + i];   // broadcast ds_read_b128
            const float s = fmaf(q0[h], kv.x, q1[h] * kv.y);
            const float e = __expf(s);             // |s|<~1: shift-free exact
            l[h] += e;
            o0[h] = fmaf(e, kv.z, o0[h]);
            o1[h] = fmaf(e, kv.w, o1[h]);
        }
    }
#pragma unroll
    for (int h = 0; h < HH; ++h) {
        s_part[vq][h*3+0][u] = l[h];
        s_part[vq][h*3+1][u] = o0[h];
        s_part[vq][h*3+2][u] = o1[h];
    }
    __syncthreads();                               // B2: partials ready

    // ---------------- epilogue (vq==0 waves only) -------------------------
    if (vq == 0) {
        float o[HD];
#pragma unroll
        for (int h = 0; h < HH; ++h) {
            float L = 0.f, O0 = 0.f, O1 = 0.f;
#pragma unroll
            for (int j = 0; j < 4; ++j) {
                L  += s_part[j][h*3+0][u];
                O0 += s_part[j][h*3+1][u];
                O1 += s_part[j][h*3+2][u];
            }
            const float inv = 1.f / L;
            o[2*h] = O0 * inv; o[2*h+1] = O1 * inv;
        }
        // out-proj + residual + leaky(0.3) + mean (wo/bo scalar-broadcast)
        const float* woc = wo + c * (HD * FF);
        const float* boc = bo + c * FF;
        float gsum = 0.f;
#pragma unroll
        for (int f = 0; f < FF; ++f) {
            float acc = boc[f];
#pragma unroll
            for (int hd = 0; hd < HD; ++hd) acc = fmaf(o[hd], woc[hd*FF + f], acc);
            const float a = xv[EI[f]] + acc;
            gsum += (a > 0.f) ? a : 0.3f * a;
        }
        const float g = gsum * (1.f / FF) + pos[c*UU + u];
        s_g[u] = g;
        g_out[(size_t)bc*UU + u] = g;
    }
    __syncthreads();                               // B3: s_g ready (frees s_part)

    // ---------------- P2: graph qkv partials; thread = (u, quarter) ------
    float aq = 0.f, ak = 0.f, av = 0.f;
#pragma unroll 4
    for (int i = 0; i < 32; ++i) {
        const int u2 = vq*32 + i;                  // wave-uniform
        const float gu = s_g[u2];                  // broadcast
        aq = fmaf(gu, gwq[u2*UU + u], aq);         // coalesced across u
        ak = fmaf(gu, gwk[u2*UU + u], ak);
        av = fmaf(gu, gwv[u2*UU + u], av);
    }
    s_gr[vq][0][u] = aq; s_gr[vq][1][u] = ak; s_gr[vq][2][u] = av;
    __syncthreads();                               // B4

    // ---------------- P3: final sums + stores -----------------------------
    if (vq < 3) {
        const float s = s_gr[0][vq][u] + s_gr[1][vq][u]
                      + s_gr[2][vq][u] + s_gr[3][vq][u];
        if (vq == 0)
            gq_out[(size_t)bc*UU + u] = (s + gbq[u]) * 0.17677669529663687f;
        else if (vq == 1)
            gk_out[(size_t)bc*UU + u] = s + gbk[u];
        else
            gv_out[(size_t)bc*UU + u] = s + gbv[u];
    }
}

// ---------------------------------------------------------------------------
// K2: graph attention + out-proj + residual. block=(b,q), 256 threads.
// ---------------------------------------------------------------------------
#define GHH 4
__global__ __launch_bounds__(256) void k2_graph(
    const float* __restrict__ gq, const float* __restrict__ gk,
    const float* __restrict__ gv, const float* __restrict__ gwo,
    const float* __restrict__ gbo, float* __restrict__ out)
{
    const int bq = blockIdx.x;
    const int b  = bq / CC;
    const int t  = threadIdx.x;

    __shared__ float s_q[UU];
    __shared__ float s_e[GHH][CC];
    __shared__ float s_pa[2][UU];   // o partials
    __shared__ float s_pl[2][UU];   // l partials
    __shared__ float s_o[UU];
    __shared__ float s_p3[2][UU];

    float gval = 0.f;
    if (t < UU) {
        gval  = out[(size_t)bq*UU + t];            // g (written by K1)
        s_q[t] = gq[(size_t)bq*UU + t];            // already scaled
    }
    __syncthreads();

    // phase 1: scores+exp; thread = (k, head-pair)
    if (t < 200) {
        const int k  = (t < 100) ? t : t - 100;
        const int h0 = (t < 100) ? 0 : 2;
        const float4* krow = (const float4*)(gk + ((size_t)b*CC + k)*UU);
        const float4* q4   = (const float4*)s_q;   // uniform -> broadcast
#pragma unroll
        for (int hh = 0; hh < 2; ++hh) {
            const int h = h0 + hh;
            float s = 0.f;
#pragma unroll
            for (int i = 0; i < 8; ++i) {
                const float4 kf = krow[h*8 + i];
                const float4 qf = q4[h*8 + i];
                s = fmaf(qf.x, kf.x, s); s = fmaf(qf.y, kf.y, s);
                s = fmaf(qf.z, kf.z, s); s = fmaf(qf.w, kf.w, s);
            }
            s_e[h][k] = __expf(s);                 // scores tiny: shift-free
        }
    }
    __syncthreads();

    // phase 2: o/l partials; thread = (d, k-half)
    {
        const int d = t & 127, kh = t >> 7, h = d >> 5;
        const float* vcol = gv + (size_t)b*CC*UU + d;
        float l = 0.f, o = 0.f;
#pragma unroll 5
        for (int i = 0; i < 50; ++i) {
            const int k = kh*50 + i;
            const float e = s_e[h][k];
            l += e;
            o = fmaf(e, vcol[(size_t)k*UU], o);    // coalesced across d
        }
        s_pa[kh][d] = o; s_pl[kh][d] = l;
    }
    __syncthreads();
    if (t < UU) s_o[t] = (s_pa[0][t] + s_pa[1][t]) / (s_pl[0][t] + s_pl[1][t]);
    __syncthreads();

    // phase 3: out-proj partials; thread = (u, hd-half)
    {
        const int u = t & 127, half = t >> 7;
        float acc = 0.f;
#pragma unroll 4
        for (int i = 0; i < 64; ++i) {
            const int hd = half*64 + i;
            acc = fmaf(s_o[hd], gwo[hd*UU + u], acc);  // coalesced across u
        }
        s_p3[half][u] = acc;
    }
    __syncthreads();
    if (t < UU)
        out[(size_t)bq*UU + t] = gval + s_p3[0][t] + s_p3[1][t] + gbo[t];
}

extern "C" void kernel_launch(void* const* d_in, const int* in_sizes, int n_in,
                              void* d_out, int out_size, void* d_ws, size_t ws_size,
                              hipStream_t stream)
{
    (void)in_sizes; (void)n_in; (void)out_size; (void)ws_size;
    const float* x   = (const float*)d_in[0];
    const float* wq  = (const float*)d_in[1];
    const float* bq  = (const float*)d_in[2];
    const float* wk  = (const float*)d_in[3];
    const float* bk  = (const float*)d_in[4];
    const float* wv  = (const float*)d_in[5];
    const float* bv  = (const float*)d_in[6];
    const float* wo  = (const float*)d_in[7];
    const float* bo  = (const float*)d_in[8];
    const float* pos = (const float*)d_in[9];
    const float* gwq = (const float*)d_in[10];
    const float* gbq = (const float*)d_in[11];
    const float* gwk = (const float*)d_in[12];
    const float* gbk = (const float*)d_in[13];
    const float* gwv = (const float*)d_in[14];
    const float* gbv = (const float*)d_in[15];
    const float* gwo = (const float*)d_in[16];
    const float* gbo = (const float*)d_in[17];
    float* out = (float*)d_out;
    float* ws  = (float*)d_ws;

    float* gq_ws = ws;              // [8*100*128]
    float* gk_ws = ws + 102400;
    float* gv_ws = ws + 204800;

    k1_chunk_mha<<<NB*CC, 512, 0, stream>>>(x, wq, bq, wk, bk, wv, bv, wo, bo,
        pos, gwq, gbq, gwk, gbk, gwv, gbv, out, gq_ws, gk_ws, gv_ws);
    k2_graph<<<NB*CC, 256, 0, stream>>>(gq_ws, gk_ws, gv_ws, gwo, gbo, out);
}